// Round 3
// baseline (661.266 us; speedup 1.0000x reference)
//
#include <hip/hip_runtime.h>
#include <hip/hip_bf16.h>
#include <math.h>

typedef unsigned short u16;
typedef __attribute__((ext_vector_type(8))) short short8;     // 8 bf16 (4 VGPRs)
typedef __attribute__((ext_vector_type(4))) float f32x4;
typedef __attribute__((ext_vector_type(4))) unsigned short ushort4v;
typedef __attribute__((ext_vector_type(8))) unsigned short ushort8v;

#define DEV static __device__ __forceinline__

DEV u16 f2bf(float f) {
    unsigned int x = __builtin_bit_cast(unsigned int, f);
    x += 0x7fffu + ((x >> 16) & 1u);      // round-to-nearest-even
    return (u16)(x >> 16);
}
DEV float bf2f(u16 u) {
    unsigned int x = ((unsigned int)u) << 16;
    return __builtin_bit_cast(float, x);
}
// pack two f32 -> two bf16 (truncating) in one v_perm_b32
DEV unsigned int pk_bf_trunc(float lo, float hi) {
    return __builtin_amdgcn_perm(__builtin_bit_cast(unsigned int, hi),
                                 __builtin_bit_cast(unsigned int, lo), 0x07060302u);
}

// async global->LDS, 16B per lane; LDS dest = wave-uniform base + lane*16
DEV void gl_lds16(const u16* g, u16* l) {
    __builtin_amdgcn_global_load_lds(
        (const __attribute__((address_space(1))) void*)g,
        (__attribute__((address_space(3))) void*)l, 16, 0, 0);
}

DEV short8 ldsv(const u16* p) { return *(const short8*)p; }

// ---------------------------------------------------------------------------
// x fp32 -> bf16, 1 unit = 8 elems. grid = n/(256*8)
// ---------------------------------------------------------------------------
__global__ __launch_bounds__(256) void k_x2bf(
    const float* __restrict__ in, u16* __restrict__ out)
{
    int idx = blockIdx.x * 256 + threadIdx.x;
    const float4* p = (const float4*)in + (size_t)idx * 2;
    float4 a = p[0], b = p[1];
    ushort8v v;
    v[0] = f2bf(a.x); v[1] = f2bf(a.y); v[2] = f2bf(a.z); v[3] = f2bf(a.w);
    v[4] = f2bf(b.x); v[5] = f2bf(b.y); v[6] = f2bf(b.z); v[7] = f2bf(b.w);
    *(ushort8v*)(out + (size_t)idx * 8) = v;
}

// ---------------------------------------------------------------------------
// Transpose-convert: out[c][r] = bf16(in[r][c]).  grid = (C/64, R/64), 256 thr
// ---------------------------------------------------------------------------
__global__ __launch_bounds__(256) void k_transpose_bf16(
    const float* __restrict__ in, u16* __restrict__ out, int R, int C)
{
    __shared__ u16 t[64][72];
    int r0 = blockIdx.y * 64, c0 = blockIdx.x * 64;
    int tid = threadIdx.x;
    for (int i = 0; i < 4; ++i) {
        int u = tid + i * 256;                 // 1024 float4 units
        int r = u >> 4, c4 = (u & 15) * 4;
        const float4 v = *(const float4*)(in + (size_t)(r0 + r) * C + c0 + c4);
        t[c4 + 0][r] = f2bf(v.x); t[c4 + 1][r] = f2bf(v.y);
        t[c4 + 2][r] = f2bf(v.z); t[c4 + 3][r] = f2bf(v.w);
    }
    __syncthreads();
    for (int i = 0; i < 4; ++i) {
        int u = tid + i * 256;                 // 1024 ushort4 units
        int c = u >> 4, r4 = (u & 15) * 4;
        ushort4v v;
        v[0] = t[c][r4]; v[1] = t[c][r4 + 1]; v[2] = t[c][r4 + 2]; v[3] = t[c][r4 + 3];
        *(ushort4v*)(out + (size_t)(c0 + c) * R + r0 + r4) = v;
    }
}

// ---------------------------------------------------------------------------
// 256x256-tile 8-phase MFMA bf16 GEMM (T2+T3+T4+T5 template, m201-style).
// BK=64, 512 threads = 8 waves (2M x 4N), per-wave C = 128x64.
// Counted s_waitcnt vmcnt(4) once per K-tile; never 0 in steady state.
// MODE 0: scatter to Q/K/V [B,H,S,D] bf16.  MODE 1: fp32 row-major out.
// ---------------------------------------------------------------------------
template <int MODE>
__global__ __launch_bounds__(512, 2) void k_gemm256(
    const u16* __restrict__ A, const u16* __restrict__ Bt,
    u16* __restrict__ outQ, u16* __restrict__ outK, u16* __restrict__ outV,
    float* __restrict__ outF, int M, int N, int K)
{
    __shared__ u16 sA[2][2][128 * 64];
    __shared__ u16 sB[2][2][128 * 64];
    const int tid = threadIdx.x;
    const int lane = tid & 63, wid = tid >> 6;
    const int wm = wid >> 2, wn = wid & 3;
    const int lm = lane & 15, lq = lane >> 4;
    const int row0 = blockIdx.y * 256, col0 = blockIdx.x * 256;

    const int rl = lane >> 3;
    const int clog = (lane & 7) ^ rl;
    const u16* gA = A  + (size_t)(row0 + rl) * K + clog * 8;
    const u16* gB = Bt + (size_t)(col0 + rl) * K + clog * 8;
    const int rg = wid * 16;                     // this wave's 16-row group

    auto stA = [&](int bb, int h, int kt) {
        const u16* g = gA + (size_t)(h * 128 + rg) * K + (size_t)kt * 64;
        u16* l = &sA[bb][h][rg * 64];
        gl_lds16(g, l);
        gl_lds16(g + (size_t)8 * K, l + 512);
    };
    auto stB = [&](int bb, int h, int kt) {
        const u16* g = gB + (size_t)(h * 128 + rg) * K + (size_t)kt * 64;
        u16* l = &sB[bb][h][rg * 64];
        gl_lds16(g, l);
        gl_lds16(g + (size_t)8 * K, l + 512);
    };

    const int sw  = lm & 7;
    const int axr = lm * 64;                           // A row base (+ t*1024)
    const int bxr = ((wn & 1) * 64 + lm) * 64;         // B row base within half
    const int co0 = ((lq ^ sw) << 3);                  // kk=0 chunk offset
    const int co1 = (((lq | 4) ^ sw) << 3);            // kk=1 chunk offset

    f32x4 acc[8][4];
#pragma unroll
    for (int a = 0; a < 8; ++a)
#pragma unroll
        for (int b = 0; b < 4; ++b) acc[a][b] = (f32x4){0.f, 0.f, 0.f, 0.f};

    short8 af[4][2], bf[4][2];
    const int NT = K >> 6;                       // K-tiles (even)

    // --- prologue: tile0 all 4 halves, tile1 B halves; drain tile0 only ---
    stB(0, 0, 0); stB(0, 1, 0); stA(0, 0, 0); stA(0, 1, 0);
    stB(1, 0, 1); stB(1, 1, 1);
    asm volatile("s_waitcnt vmcnt(4)" ::: "memory");
    __builtin_amdgcn_s_barrier();

    auto tile_step = [&](int T, int buf) {
        const u16* pA = &sA[buf][wm][0];
        const u16* pB = &sB[buf][wn >> 1][0];
        const int nb = buf ^ 1;
        const bool p1ok = (T + 1 < NT);
        const bool p2ok = (T + 2 < NT);

        // ---- phase 1: read A[it 0-3] + B[jt 0-1]; stage A-half0(T+1) ----
#pragma unroll
        for (int t = 0; t < 4; ++t) {
            af[t][0] = ldsv(pA + axr + t * 1024 + co0);
            af[t][1] = ldsv(pA + axr + t * 1024 + co1);
        }
#pragma unroll
        for (int j = 0; j < 2; ++j) {
            bf[j][0] = ldsv(pB + bxr + j * 1024 + co0);
            bf[j][1] = ldsv(pB + bxr + j * 1024 + co1);
        }
        if (p1ok) stA(nb, 0, T + 1);
        asm volatile("s_waitcnt lgkmcnt(8)" ::: "memory");
        __builtin_amdgcn_s_barrier();
        asm volatile("s_waitcnt lgkmcnt(0)" ::: "memory");
        __builtin_amdgcn_s_setprio(1);
#pragma unroll
        for (int t = 0; t < 4; ++t)
#pragma unroll
            for (int j = 0; j < 2; ++j)
#pragma unroll
                for (int kk = 0; kk < 2; ++kk)
                    acc[t][j] = __builtin_amdgcn_mfma_f32_16x16x32_bf16(
                        af[t][kk], bf[j][kk], acc[t][j], 0, 0, 0);
        __builtin_amdgcn_s_setprio(0);
        __builtin_amdgcn_s_barrier();

        // ---- phase 2: read B[jt 2-3]; stage A-half1(T+1); quad (0-3,2-3) ----
#pragma unroll
        for (int j = 0; j < 2; ++j) {
            bf[2 + j][0] = ldsv(pB + bxr + (2 + j) * 1024 + co0);
            bf[2 + j][1] = ldsv(pB + bxr + (2 + j) * 1024 + co1);
        }
        if (p1ok) stA(nb, 1, T + 1);
        __builtin_amdgcn_s_barrier();
        asm volatile("s_waitcnt lgkmcnt(0)" ::: "memory");
        __builtin_amdgcn_s_setprio(1);
#pragma unroll
        for (int t = 0; t < 4; ++t)
#pragma unroll
            for (int j = 0; j < 2; ++j)
#pragma unroll
                for (int kk = 0; kk < 2; ++kk)
                    acc[t][2 + j] = __builtin_amdgcn_mfma_f32_16x16x32_bf16(
                        af[t][kk], bf[2 + j][kk], acc[t][2 + j], 0, 0, 0);
        __builtin_amdgcn_s_setprio(0);
        __builtin_amdgcn_s_barrier();

        // ---- phase 3: read A[it 4-7]; stage B-half0(T+2); quad (4-7,2-3) ----
#pragma unroll
        for (int t = 0; t < 4; ++t) {
            af[t][0] = ldsv(pA + axr + (4 + t) * 1024 + co0);
            af[t][1] = ldsv(pA + axr + (4 + t) * 1024 + co1);
        }
        if (p2ok) stB(buf, 0, T + 2);
        __builtin_amdgcn_s_barrier();
        asm volatile("s_waitcnt lgkmcnt(0)" ::: "memory");
        __builtin_amdgcn_s_setprio(1);
#pragma unroll
        for (int t = 0; t < 4; ++t)
#pragma unroll
            for (int j = 0; j < 2; ++j)
#pragma unroll
                for (int kk = 0; kk < 2; ++kk)
                    acc[4 + t][2 + j] = __builtin_amdgcn_mfma_f32_16x16x32_bf16(
                        af[t][kk], bf[2 + j][kk], acc[4 + t][2 + j], 0, 0, 0);
        __builtin_amdgcn_s_setprio(0);
        __builtin_amdgcn_s_barrier();

        // ---- phase 4: stage B-half1(T+2); counted vmcnt; quad (4-7,0-1) ----
        if (p2ok) {
            stB(buf, 1, T + 2);
            asm volatile("s_waitcnt vmcnt(4)" ::: "memory");
        } else {
            asm volatile("s_waitcnt vmcnt(0)" ::: "memory");
        }
        __builtin_amdgcn_s_barrier();
        __builtin_amdgcn_s_setprio(1);
#pragma unroll
        for (int t = 0; t < 4; ++t)
#pragma unroll
            for (int j = 0; j < 2; ++j)
#pragma unroll
                for (int kk = 0; kk < 2; ++kk)
                    acc[4 + t][j] = __builtin_amdgcn_mfma_f32_16x16x32_bf16(
                        af[t][kk], bf[j][kk], acc[4 + t][j], 0, 0, 0);
        __builtin_amdgcn_s_setprio(0);
        __builtin_amdgcn_s_barrier();
    };

    for (int T = 0; T < NT; T += 2) {
        tile_step(T, 0);
        tile_step(T + 1, 1);
    }
    asm volatile("s_waitcnt vmcnt(0)" ::: "memory");

    if (MODE == 0) {
        int k3 = col0 >> 11;                   // uniform per block (256 | 2048)
        u16* dst = (k3 == 0) ? outQ : (k3 == 1) ? outK : outV;
#pragma unroll
        for (int it = 0; it < 8; ++it)
#pragma unroll
            for (int jt = 0; jt < 4; ++jt) {
                int c = col0 + wn * 64 + jt * 16 + lm;
                int hd = c & 2047, h = hd >> 7, d = hd & 127;
#pragma unroll
                for (int i = 0; i < 4; ++i) {
                    int r = row0 + wm * 128 + it * 16 + lq * 4 + i;
                    int b = r >> 11, s = r & 2047;
                    dst[((size_t)(b * 16 + h) * 2048 + s) * 128 + d] = f2bf(acc[it][jt][i]);
                }
            }
    } else {
#pragma unroll
        for (int it = 0; it < 8; ++it)
#pragma unroll
            for (int jt = 0; jt < 4; ++jt) {
                int c = col0 + wn * 64 + jt * 16 + lm;
#pragma unroll
                for (int i = 0; i < 4; ++i) {
                    int r = row0 + wm * 128 + it * 16 + lq * 4 + i;
                    outF[(size_t)r * N + c] = acc[it][jt][i];
                }
            }
    }
}

// ---------------------------------------------------------------------------
// RMSNorm + RoPE, in-place on [B,H,S,D] bf16 rows, then *oscale.
// For Q, oscale = 1/sqrt(D) * log2(e)  (base-2 softmax pre-scaling).
// ---------------------------------------------------------------------------
__global__ __launch_bounds__(256) void k_normrope(
    u16* __restrict__ X, const float* __restrict__ w, float oscale)
{
    int row = blockIdx.x * 4 + (threadIdx.x >> 6);
    int t = threadIdx.x & 63;
    int s = row & 2047;                        // S = 2048
    u16* p = X + (size_t)row * 128;
    float x0 = bf2f(p[t]), x1 = bf2f(p[t + 64]);
    float ss = x0 * x0 + x1 * x1;
    for (int m = 1; m < 64; m <<= 1) ss += __shfl_xor(ss, m);
    float r = rsqrtf(ss * (1.0f / 128.0f) + 0.01f);
    float a = x0 * r * w[t];
    float b = x1 * r * w[t + 64];
    float freq = exp2f(-13.287712379549449f * ((float)t * (1.0f / 64.0f)));
    float ang = (float)s * freq;
    float sn, c;
    sincosf(ang, &sn, &c);
    p[t]      = f2bf((a * c - b * sn) * oscale);
    p[t + 64] = f2bf((b * c + a * sn) * oscale);
}

// ---------------------------------------------------------------------------
// V transpose per head: [B,H,S,D] -> [B,H,D,S]. grid = (S/64, B*H)
// ---------------------------------------------------------------------------
__global__ __launch_bounds__(256) void k_vtrans(
    const u16* __restrict__ Vh, u16* __restrict__ Vt, int S)
{
    __shared__ u16 t[128][68];
    int bh = blockIdx.y, s0 = blockIdx.x * 64;
    int tid = threadIdx.x;
    const u16* src = Vh + ((size_t)bh * S + s0) * 128;
    for (int i = 0; i < 4; ++i) {
        int u = tid + i * 256;
        int r = u >> 4, c8 = (u & 15) * 8;
        ushort8v v = *(const ushort8v*)(src + (size_t)r * 128 + c8);
        for (int j = 0; j < 8; ++j) t[c8 + j][r] = v[j];
    }
    __syncthreads();
    u16* dst = Vt + (size_t)bh * 128 * S + s0;
    for (int i = 0; i < 8; ++i) {
        int u = tid + i * 256;
        int d = u >> 4, s4 = (u & 15) * 4;
        ushort4v v;
        v[0] = t[d][s4]; v[1] = t[d][s4 + 1]; v[2] = t[d][s4 + 2]; v[3] = t[d][s4 + 3];
        *(ushort4v*)(dst + (size_t)d * S + s4) = v;
    }
}

// ---------------------------------------------------------------------------
// Causal flash attention, 32 q-rows per wave (2 column-groups c=0,1).
// grid = (16, B*H), q-block = 128 rows, KV tiles of 64, LPT order.
// Per KV tile: 32 QK MFMA + 32 PV MFMA on 36 ds ops (each kf/vf LDS fragment
// feeds 2 MFMA -> half the LDS+barrier cost per FLOP vs 16-q version).
// Phase-offset single-buffer staging: K(kb+1) issued after post-QK barrier
// (covered by softmax+PV), V(kb+1) after post-PV barrier (covered by next QK).
// Q pre-scaled by 1/sqrt(D)*log2e -> base-2 softmax. LDS 48KB. ~190 VGPR.
// ---------------------------------------------------------------------------
DEV void flash_core2(int lq, int lm, const u16* __restrict__ sKf,
                     const short8 qf[4][2], f32x4 sacc[4][2])
{
#pragma unroll
    for (int nt = 0; nt < 4; ++nt)
#pragma unroll
        for (int c = 0; c < 2; ++c) sacc[nt][c] = (f32x4){0.f, 0.f, 0.f, 0.f};
#pragma unroll
    for (int nt = 0; nt < 4; ++nt)
#pragma unroll
        for (int kc = 0; kc < 4; ++kc) {
            short8 kf = ldsv(sKf + (nt * 16 + lm) * 128 +
                             (((kc * 4 + lq) ^ lm) << 3));
#pragma unroll
            for (int c = 0; c < 2; ++c)
                sacc[nt][c] = __builtin_amdgcn_mfma_f32_16x16x32_bf16(
                    kf, qf[kc][c], sacc[nt][c], 0, 0, 0);
        }
}

DEV void flash_softmax_pv2(int lq, int lm, const u16* __restrict__ sVf,
                           f32x4 oacc[8][2], float mprev[2], float lsum[2],
                           u16* __restrict__ sPw, f32x4 sacc[4][2])
{
    float alpha[2];
#pragma unroll
    for (int c = 0; c < 2; ++c) {
        float mx = sacc[0][c][0];
#pragma unroll
        for (int nt = 0; nt < 4; ++nt)
#pragma unroll
            for (int i = 0; i < 4; ++i) mx = fmaxf(mx, sacc[nt][c][i]);
        mx = fmaxf(mx, __shfl_xor(mx, 16));
        mx = fmaxf(mx, __shfl_xor(mx, 32));
        float mnew = fmaxf(mprev[c], mx);
        alpha[c] = exp2f(mprev[c] - mnew);
        float rs = 0.0f;
#pragma unroll
        for (int nt = 0; nt < 4; ++nt)
#pragma unroll
            for (int i = 0; i < 4; ++i) {
                float pv = exp2f(sacc[nt][c][i] - mnew);  // pre-scaled by log2e
                sacc[nt][c][i] = pv;
                rs += pv;
            }
        rs += __shfl_xor(rs, 16);
        rs += __shfl_xor(rs, 32);
        lsum[c] = lsum[c] * alpha[c] + rs;
        mprev[c] = mnew;

        // P -> per-wave LDS rows [c*16+lm] (truncating pack; P in [0,1])
#pragma unroll
        for (int nt = 0; nt < 4; ++nt) {
            uint2 pk;
            pk.x = pk_bf_trunc(sacc[nt][c][0], sacc[nt][c][1]);
            pk.y = pk_bf_trunc(sacc[nt][c][2], sacc[nt][c][3]);
            *(uint2*)(sPw + (c * 16 + lm) * 64 +
                      ((((nt << 1) + (lq >> 1)) ^ (lm & 7)) << 3) + ((lq & 1) << 2)) = pk;
        }
    }

    float alphar[2][4];
#pragma unroll
    for (int c = 0; c < 2; ++c)
#pragma unroll
        for (int i = 0; i < 4; ++i) alphar[c][i] = __shfl(alpha[c], lq * 4 + i, 16);
#pragma unroll
    for (int f = 0; f < 8; ++f)
#pragma unroll
        for (int c = 0; c < 2; ++c)
#pragma unroll
            for (int i = 0; i < 4; ++i) oacc[f][c][i] *= alphar[c][i];

    short8 pf[2][2];
#pragma unroll
    for (int kc = 0; kc < 2; ++kc)
#pragma unroll
        for (int c = 0; c < 2; ++c)
            pf[kc][c] = ldsv(sPw + (c * 16 + lm) * 64 +
                             (((kc * 4 + lq) ^ (lm & 7)) << 3));
#pragma unroll
    for (int f = 0; f < 8; ++f)
#pragma unroll
        for (int kc = 0; kc < 2; ++kc) {
            short8 vf = ldsv(sVf + (f * 16 + lm) * 64 +
                             (((kc * 4 + lq) ^ (lm & 7)) << 3));
#pragma unroll
            for (int c = 0; c < 2; ++c)
                oacc[f][c] = __builtin_amdgcn_mfma_f32_16x16x32_bf16(
                    pf[kc][c], vf, oacc[f][c], 0, 0, 0);
        }
}

__global__ __launch_bounds__(256, 2) void k_flash(
    const u16* __restrict__ Qh, const u16* __restrict__ Kh,
    const u16* __restrict__ Vt, u16* __restrict__ ctx, int S)
{
    __shared__ u16 sK[64 * 128];                // 16 KB [kv][d], swizzled
    __shared__ u16 sV[128 * 64];                // 16 KB [d][kv], swizzled
    __shared__ u16 sP[4 * 32 * 64];             // 16 KB per-wave [32][64]
    int qi = 15 - (int)blockIdx.x;              // LPT: big blocks first
    int bh = blockIdx.y;
    int b = bh >> 4, h = bh & 15;
    int tid = threadIdx.x, lane = tid & 63, w = tid >> 6;
    int lm = lane & 15, lq = lane >> 4;
    const u16* qbase = Qh + (size_t)bh * S * 128;
    u16* sPw = &sP[w * 32 * 64];

    int kck = lm ^ (w * 4 + lq);
    const u16* kg = Kh + (size_t)bh * S * 128 + (size_t)(w * 4 + lq) * 128 + kck * 8;
    int hi3 = lane >> 3, c3 = lane & 7;
    int vck = c3 ^ (hi3 & 7);
    const u16* vg = Vt + (size_t)bh * 128 * S + (size_t)(w * 8 + hi3) * S + vck * 8;

    auto stageK = [&](int kb) {
        const u16* g = kg + (size_t)kb * (64 * 128);
        for (int i = 0; i < 4; ++i)
            gl_lds16(g + i * (16 * 128), sK + (i * 16 + w * 4) * 128);
    };
    auto stageV = [&](int kb) {
        const u16* g = vg + kb * 64;
        for (int i = 0; i < 4; ++i)
            gl_lds16(g + (size_t)(i * 32) * S, sV + (i * 32 + w * 8) * 64);
    };

    int qw0 = qi * 128 + w * 32;                // this wave's first q row
    short8 qf[4][2];
#pragma unroll
    for (int kc = 0; kc < 4; ++kc)
#pragma unroll
        for (int c = 0; c < 2; ++c)
            qf[kc][c] = *(const short8*)(qbase + (size_t)(qw0 + c * 16 + lm) * 128 +
                                         kc * 32 + lq * 8);

    f32x4 oacc[8][2];
#pragma unroll
    for (int f = 0; f < 8; ++f)
#pragma unroll
        for (int c = 0; c < 2; ++c) oacc[f][c] = (f32x4){0.f, 0.f, 0.f, 0.f};
    float mprev[2] = {-1e30f, -1e30f}, lsum[2] = {0.0f, 0.0f};

    stageK(0);
    stageV(0);
    __syncthreads();

    f32x4 sacc[4][2];
    auto mask_tile = [&](int kb) {
#pragma unroll
        for (int nt = 0; nt < 4; ++nt)
#pragma unroll
            for (int c = 0; c < 2; ++c)
#pragma unroll
                for (int i = 0; i < 4; ++i) {
                    int kv = kb * 64 + nt * 16 + lq * 4 + i;
                    if (kv > qw0 + c * 16 + lm) sacc[nt][c][i] = -1e30f;
                }
    };

    int last = 2 * qi + 1;                      // final (masked) KV tile
    for (int kb = 0; kb < last; ++kb) {
        flash_core2(lq, lm, sK, qf, sacc);
        if (kb == last - 1) mask_tile(kb);      // block-uniform branch
        __syncthreads();                        // A: sK free; drains V(kb) loads
        stageK(kb + 1);                         // covered by softmax+PV
        flash_softmax_pv2(lq, lm, sV, oacc, mprev, lsum, sPw, sacc);
        __syncthreads();                        // B: sV free; drains K(kb+1) loads
        stageV(kb + 1);                         // covered by next QK
    }
    flash_core2(lq, lm, sK, qf, sacc);
    mask_tile(last);
    __syncthreads();                            // drains V(last) loads
    flash_softmax_pv2(lq, lm, sV, oacc, mprev, lsum, sPw, sacc);

    float linv[2][4];
#pragma unroll
    for (int c = 0; c < 2; ++c)
#pragma unroll
        for (int i = 0; i < 4; ++i)
            linv[c][i] = 1.0f / __shfl(lsum[c], lq * 4 + i, 16);
    u16* obase = ctx + (size_t)b * S * 2048 + h * 128;
#pragma unroll
    for (int f = 0; f < 8; ++f) {
        int d = f * 16 + lm;
#pragma unroll
        for (int c = 0; c < 2; ++c)
#pragma unroll
            for (int i = 0; i < 4; ++i) {
                int s = qw0 + c * 16 + lq * 4 + i;
                obase[(size_t)s * 2048 + d] = f2bf(oacc[f][c][i] * linv[c][i]);
            }
    }
}

// ---------------------------------------------------------------------------
extern "C" void kernel_launch(void* const* d_in, const int* in_sizes, int n_in,
                              void* d_out, int out_size, void* d_ws, size_t ws_size,
                              hipStream_t stream)
{
    const float* x        = (const float*)d_in[0];
    const float* w_qkv    = (const float*)d_in[1];
    const float* w_proj   = (const float*)d_in[2];
    const float* q_norm_w = (const float*)d_in[3];
    const float* k_norm_w = (const float*)d_in[4];
    float* out = (float*)d_out;

    const int B = 4, S = 2048, E = 2048, H = 16;
    const int M  = B * S;        // 8192
    const int N1 = 3 * E;        // 6144
    const int N2 = E;            // 2048
    // 1/sqrt(128) * log2(e)
    const float QSCALE = 0.12751743f;

    char* ws = (char*)d_ws;
    size_t off = 0;
    auto alloc = [&](size_t bytes) {
        char* p = ws + off;
        off += (bytes + 255) & ~(size_t)255;
        return p;
    };
    u16* Wpt  = (u16*)alloc((size_t)E * E * 2);        // live to end
    char* regR = alloc((size_t)M * N1 * 2);
    u16* Wqt  = (u16*)regR;                            //   dead after GEMM1
    u16* ctxp = (u16*)regR;                            //   written by flash
    u16* Qh = (u16*)alloc((size_t)M * E * 2);
    u16* Kh = (u16*)alloc((size_t)M * E * 2);
    u16* Vh = (u16*)alloc((size_t)M * E * 2);
    char* regV = alloc((size_t)M * E * 2);
    u16* xb = (u16*)regV;                              //   dead after GEMM1
    u16* Vt = (u16*)regV;                              //   written by vtrans

    // 0. x -> bf16
    k_x2bf<<<(M * E) / (256 * 8), 256, 0, stream>>>(x, xb);
    // 1. weight transpose/convert
    k_transpose_bf16<<<dim3(N1 / 64, E / 64), 256, 0, stream>>>(w_qkv, Wqt, E, N1);
    k_transpose_bf16<<<dim3(N2 / 64, E / 64), 256, 0, stream>>>(w_proj, Wpt, E, N2);
    // 2. fused QKV projection, scatter to [B,H,S,D]  (256x256 8-phase)
    k_gemm256<0><<<dim3(N1 / 256, M / 256), 512, 0, stream>>>(
        xb, Wqt, Qh, Kh, Vh, nullptr, M, N1, E);
    // 3. RMSNorm + RoPE (Q additionally pre-scaled for base-2 softmax)
    k_normrope<<<(B * H * S) / 4, 256, 0, stream>>>(Qh, q_norm_w, QSCALE);
    k_normrope<<<(B * H * S) / 4, 256, 0, stream>>>(Kh, k_norm_w, 1.0f);
    // 4. transpose V per head (overwrites xb region — xb dead by now)
    k_vtrans<<<dim3(S / 64, B * H), 256, 0, stream>>>(Vh, Vt, S);
    // 5. causal flash attention -> ctx [B,S,H*D]  (128-row q-blocks)
    k_flash<<<dim3(S / 128, B * H), 256, 0, stream>>>(Qh, Kh, Vt, ctxp, S);
    // 6. output projection -> fp32 out  (256x256 8-phase)
    k_gemm256<1><<<dim3(N2 / 256, M / 256), 512, 0, stream>>>(
        ctxp, Wpt, nullptr, nullptr, nullptr, out, M, N2, E);
}

// Round 4
// 600.900 us; speedup vs baseline: 1.1005x; 1.1005x over previous
//
#include <hip/hip_runtime.h>
#include <hip/hip_bf16.h>
#include <math.h>

typedef unsigned short u16;
typedef __attribute__((ext_vector_type(8))) short short8;     // 8 bf16 (4 VGPRs)
typedef __attribute__((ext_vector_type(4))) float f32x4;
typedef __attribute__((ext_vector_type(4))) unsigned short ushort4v;
typedef __attribute__((ext_vector_type(8))) unsigned short ushort8v;

#define DEV static __device__ __forceinline__

DEV u16 f2bf(float f) {
    unsigned int x = __builtin_bit_cast(unsigned int, f);
    x += 0x7fffu + ((x >> 16) & 1u);      // round-to-nearest-even
    return (u16)(x >> 16);
}
DEV float bf2f(u16 u) {
    unsigned int x = ((unsigned int)u) << 16;
    return __builtin_bit_cast(float, x);
}
// pack two f32 -> two bf16 (truncating) in one v_perm_b32
DEV unsigned int pk_bf_trunc(float lo, float hi) {
    return __builtin_amdgcn_perm(__builtin_bit_cast(unsigned int, hi),
                                 __builtin_bit_cast(unsigned int, lo), 0x07060302u);
}

// async global->LDS, 16B per lane; LDS dest = wave-uniform base + lane*16
DEV void gl_lds16(const u16* g, u16* l) {
    __builtin_amdgcn_global_load_lds(
        (const __attribute__((address_space(1))) void*)g,
        (__attribute__((address_space(3))) void*)l, 16, 0, 0);
}

DEV short8 ldsv(const u16* p) { return *(const short8*)p; }

// ---------------------------------------------------------------------------
// x fp32 -> bf16, 1 unit = 8 elems. grid = n/(256*8)
// ---------------------------------------------------------------------------
__global__ __launch_bounds__(256) void k_x2bf(
    const float* __restrict__ in, u16* __restrict__ out)
{
    int idx = blockIdx.x * 256 + threadIdx.x;
    const float4* p = (const float4*)in + (size_t)idx * 2;
    float4 a = p[0], b = p[1];
    ushort8v v;
    v[0] = f2bf(a.x); v[1] = f2bf(a.y); v[2] = f2bf(a.z); v[3] = f2bf(a.w);
    v[4] = f2bf(b.x); v[5] = f2bf(b.y); v[6] = f2bf(b.z); v[7] = f2bf(b.w);
    *(ushort8v*)(out + (size_t)idx * 8) = v;
}

// ---------------------------------------------------------------------------
// Transpose-convert: out[c][r] = bf16(in[r][c]).  grid = (C/64, R/64), 256 thr
// ---------------------------------------------------------------------------
__global__ __launch_bounds__(256) void k_transpose_bf16(
    const float* __restrict__ in, u16* __restrict__ out, int R, int C)
{
    __shared__ u16 t[64][72];
    int r0 = blockIdx.y * 64, c0 = blockIdx.x * 64;
    int tid = threadIdx.x;
    for (int i = 0; i < 4; ++i) {
        int u = tid + i * 256;                 // 1024 float4 units
        int r = u >> 4, c4 = (u & 15) * 4;
        const float4 v = *(const float4*)(in + (size_t)(r0 + r) * C + c0 + c4);
        t[c4 + 0][r] = f2bf(v.x); t[c4 + 1][r] = f2bf(v.y);
        t[c4 + 2][r] = f2bf(v.z); t[c4 + 3][r] = f2bf(v.w);
    }
    __syncthreads();
    for (int i = 0; i < 4; ++i) {
        int u = tid + i * 256;                 // 1024 ushort4 units
        int c = u >> 4, r4 = (u & 15) * 4;
        ushort4v v;
        v[0] = t[c][r4]; v[1] = t[c][r4 + 1]; v[2] = t[c][r4 + 2]; v[3] = t[c][r4 + 3];
        *(ushort4v*)(out + (size_t)(c0 + c) * R + r0 + r4) = v;
    }
}

// ---------------------------------------------------------------------------
// 256x256-tile 8-phase MFMA bf16 GEMM (T2+T3+T4+T5 template, m201-style).
// BK=64, 512 threads = 8 waves (2M x 4N), per-wave C = 128x64.
// Counted s_waitcnt vmcnt(4) once per K-tile; never 0 in steady state.
// MODE 0: scatter to Q/K/V [B,H,S,D] bf16.  MODE 1: fp32 row-major out.
// ---------------------------------------------------------------------------
template <int MODE>
__global__ __launch_bounds__(512, 2) void k_gemm256(
    const u16* __restrict__ A, const u16* __restrict__ Bt,
    u16* __restrict__ outQ, u16* __restrict__ outK, u16* __restrict__ outV,
    float* __restrict__ outF, int M, int N, int K)
{
    __shared__ u16 sA[2][2][128 * 64];
    __shared__ u16 sB[2][2][128 * 64];
    const int tid = threadIdx.x;
    const int lane = tid & 63, wid = tid >> 6;
    const int wm = wid >> 2, wn = wid & 3;
    const int lm = lane & 15, lq = lane >> 4;
    const int row0 = blockIdx.y * 256, col0 = blockIdx.x * 256;

    const int rl = lane >> 3;
    const int clog = (lane & 7) ^ rl;
    const u16* gA = A  + (size_t)(row0 + rl) * K + clog * 8;
    const u16* gB = Bt + (size_t)(col0 + rl) * K + clog * 8;
    const int rg = wid * 16;                     // this wave's 16-row group

    auto stA = [&](int bb, int h, int kt) {
        const u16* g = gA + (size_t)(h * 128 + rg) * K + (size_t)kt * 64;
        u16* l = &sA[bb][h][rg * 64];
        gl_lds16(g, l);
        gl_lds16(g + (size_t)8 * K, l + 512);
    };
    auto stB = [&](int bb, int h, int kt) {
        const u16* g = gB + (size_t)(h * 128 + rg) * K + (size_t)kt * 64;
        u16* l = &sB[bb][h][rg * 64];
        gl_lds16(g, l);
        gl_lds16(g + (size_t)8 * K, l + 512);
    };

    const int sw  = lm & 7;
    const int axr = lm * 64;                           // A row base (+ t*1024)
    const int bxr = ((wn & 1) * 64 + lm) * 64;         // B row base within half
    const int co0 = ((lq ^ sw) << 3);                  // kk=0 chunk offset
    const int co1 = (((lq | 4) ^ sw) << 3);            // kk=1 chunk offset

    f32x4 acc[8][4];
#pragma unroll
    for (int a = 0; a < 8; ++a)
#pragma unroll
        for (int b = 0; b < 4; ++b) acc[a][b] = (f32x4){0.f, 0.f, 0.f, 0.f};

    short8 af[4][2], bf[4][2];
    const int NT = K >> 6;                       // K-tiles (even)

    // --- prologue: tile0 all 4 halves, tile1 B halves; drain tile0 only ---
    stB(0, 0, 0); stB(0, 1, 0); stA(0, 0, 0); stA(0, 1, 0);
    stB(1, 0, 1); stB(1, 1, 1);
    asm volatile("s_waitcnt vmcnt(4)" ::: "memory");
    __builtin_amdgcn_s_barrier();

    auto tile_step = [&](int T, int buf) {
        const u16* pA = &sA[buf][wm][0];
        const u16* pB = &sB[buf][wn >> 1][0];
        const int nb = buf ^ 1;
        const bool p1ok = (T + 1 < NT);
        const bool p2ok = (T + 2 < NT);

        // ---- phase 1: read A[it 0-3] + B[jt 0-1]; stage A-half0(T+1) ----
#pragma unroll
        for (int t = 0; t < 4; ++t) {
            af[t][0] = ldsv(pA + axr + t * 1024 + co0);
            af[t][1] = ldsv(pA + axr + t * 1024 + co1);
        }
#pragma unroll
        for (int j = 0; j < 2; ++j) {
            bf[j][0] = ldsv(pB + bxr + j * 1024 + co0);
            bf[j][1] = ldsv(pB + bxr + j * 1024 + co1);
        }
        if (p1ok) stA(nb, 0, T + 1);
        asm volatile("s_waitcnt lgkmcnt(8)" ::: "memory");
        __builtin_amdgcn_s_barrier();
        asm volatile("s_waitcnt lgkmcnt(0)" ::: "memory");
        __builtin_amdgcn_s_setprio(1);
#pragma unroll
        for (int t = 0; t < 4; ++t)
#pragma unroll
            for (int j = 0; j < 2; ++j)
#pragma unroll
                for (int kk = 0; kk < 2; ++kk)
                    acc[t][j] = __builtin_amdgcn_mfma_f32_16x16x32_bf16(
                        af[t][kk], bf[j][kk], acc[t][j], 0, 0, 0);
        __builtin_amdgcn_s_setprio(0);
        __builtin_amdgcn_s_barrier();

        // ---- phase 2: read B[jt 2-3]; stage A-half1(T+1); quad (0-3,2-3) ----
#pragma unroll
        for (int j = 0; j < 2; ++j) {
            bf[2 + j][0] = ldsv(pB + bxr + (2 + j) * 1024 + co0);
            bf[2 + j][1] = ldsv(pB + bxr + (2 + j) * 1024 + co1);
        }
        if (p1ok) stA(nb, 1, T + 1);
        __builtin_amdgcn_s_barrier();
        asm volatile("s_waitcnt lgkmcnt(0)" ::: "memory");
        __builtin_amdgcn_s_setprio(1);
#pragma unroll
        for (int t = 0; t < 4; ++t)
#pragma unroll
            for (int j = 0; j < 2; ++j)
#pragma unroll
                for (int kk = 0; kk < 2; ++kk)
                    acc[t][2 + j] = __builtin_amdgcn_mfma_f32_16x16x32_bf16(
                        af[t][kk], bf[2 + j][kk], acc[t][2 + j], 0, 0, 0);
        __builtin_amdgcn_s_setprio(0);
        __builtin_amdgcn_s_barrier();

        // ---- phase 3: read A[it 4-7]; stage B-half0(T+2); quad (4-7,2-3) ----
#pragma unroll
        for (int t = 0; t < 4; ++t) {
            af[t][0] = ldsv(pA + axr + (4 + t) * 1024 + co0);
            af[t][1] = ldsv(pA + axr + (4 + t) * 1024 + co1);
        }
        if (p2ok) stB(buf, 0, T + 2);
        __builtin_amdgcn_s_barrier();
        asm volatile("s_waitcnt lgkmcnt(0)" ::: "memory");
        __builtin_amdgcn_s_setprio(1);
#pragma unroll
        for (int t = 0; t < 4; ++t)
#pragma unroll
            for (int j = 0; j < 2; ++j)
#pragma unroll
                for (int kk = 0; kk < 2; ++kk)
                    acc[4 + t][2 + j] = __builtin_amdgcn_mfma_f32_16x16x32_bf16(
                        af[t][kk], bf[2 + j][kk], acc[4 + t][2 + j], 0, 0, 0);
        __builtin_amdgcn_s_setprio(0);
        __builtin_amdgcn_s_barrier();

        // ---- phase 4: stage B-half1(T+2); counted vmcnt; quad (4-7,0-1) ----
        if (p2ok) {
            stB(buf, 1, T + 2);
            asm volatile("s_waitcnt vmcnt(4)" ::: "memory");
        } else {
            asm volatile("s_waitcnt vmcnt(0)" ::: "memory");
        }
        __builtin_amdgcn_s_barrier();
        __builtin_amdgcn_s_setprio(1);
#pragma unroll
        for (int t = 0; t < 4; ++t)
#pragma unroll
            for (int j = 0; j < 2; ++j)
#pragma unroll
                for (int kk = 0; kk < 2; ++kk)
                    acc[4 + t][j] = __builtin_amdgcn_mfma_f32_16x16x32_bf16(
                        af[t][kk], bf[j][kk], acc[4 + t][j], 0, 0, 0);
        __builtin_amdgcn_s_setprio(0);
        __builtin_amdgcn_s_barrier();
    };

    for (int T = 0; T < NT; T += 2) {
        tile_step(T, 0);
        tile_step(T + 1, 1);
    }
    asm volatile("s_waitcnt vmcnt(0)" ::: "memory");

    if (MODE == 0) {
        int k3 = col0 >> 11;                   // uniform per block (256 | 2048)
        u16* dst = (k3 == 0) ? outQ : (k3 == 1) ? outK : outV;
#pragma unroll
        for (int it = 0; it < 8; ++it)
#pragma unroll
            for (int jt = 0; jt < 4; ++jt) {
                int c = col0 + wn * 64 + jt * 16 + lm;
                int hd = c & 2047, h = hd >> 7, d = hd & 127;
#pragma unroll
                for (int i = 0; i < 4; ++i) {
                    int r = row0 + wm * 128 + it * 16 + lq * 4 + i;
                    int b = r >> 11, s = r & 2047;
                    dst[((size_t)(b * 16 + h) * 2048 + s) * 128 + d] = f2bf(acc[it][jt][i]);
                }
            }
    } else {
#pragma unroll
        for (int it = 0; it < 8; ++it)
#pragma unroll
            for (int jt = 0; jt < 4; ++jt) {
                int c = col0 + wn * 64 + jt * 16 + lm;
#pragma unroll
                for (int i = 0; i < 4; ++i) {
                    int r = row0 + wm * 128 + it * 16 + lq * 4 + i;
                    outF[(size_t)r * N + c] = acc[it][jt][i];
                }
            }
    }
}

// ---------------------------------------------------------------------------
// RMSNorm + RoPE, in-place on [B,H,S,D] bf16 rows, then *oscale.
// For Q, oscale = 1/sqrt(D) * log2(e)  (base-2 softmax pre-scaling).
// ---------------------------------------------------------------------------
__global__ __launch_bounds__(256) void k_normrope(
    u16* __restrict__ X, const float* __restrict__ w, float oscale)
{
    int row = blockIdx.x * 4 + (threadIdx.x >> 6);
    int t = threadIdx.x & 63;
    int s = row & 2047;                        // S = 2048
    u16* p = X + (size_t)row * 128;
    float x0 = bf2f(p[t]), x1 = bf2f(p[t + 64]);
    float ss = x0 * x0 + x1 * x1;
    for (int m = 1; m < 64; m <<= 1) ss += __shfl_xor(ss, m);
    float r = rsqrtf(ss * (1.0f / 128.0f) + 0.01f);
    float a = x0 * r * w[t];
    float b = x1 * r * w[t + 64];
    float freq = exp2f(-13.287712379549449f * ((float)t * (1.0f / 64.0f)));
    float ang = (float)s * freq;
    float sn, c;
    sincosf(ang, &sn, &c);
    p[t]      = f2bf((a * c - b * sn) * oscale);
    p[t + 64] = f2bf((b * c + a * sn) * oscale);
}

// ---------------------------------------------------------------------------
// V transpose per head: [B,H,S,D] -> [B,H,D,S]. grid = (S/64, B*H)
// ---------------------------------------------------------------------------
__global__ __launch_bounds__(256) void k_vtrans(
    const u16* __restrict__ Vh, u16* __restrict__ Vt, int S)
{
    __shared__ u16 t[128][68];
    int bh = blockIdx.y, s0 = blockIdx.x * 64;
    int tid = threadIdx.x;
    const u16* src = Vh + ((size_t)bh * S + s0) * 128;
    for (int i = 0; i < 4; ++i) {
        int u = tid + i * 256;
        int r = u >> 4, c8 = (u & 15) * 8;
        ushort8v v = *(const ushort8v*)(src + (size_t)r * 128 + c8);
        for (int j = 0; j < 8; ++j) t[c8 + j][r] = v[j];
    }
    __syncthreads();
    u16* dst = Vt + (size_t)bh * 128 * S + s0;
    for (int i = 0; i < 8; ++i) {
        int u = tid + i * 256;
        int d = u >> 4, s4 = (u & 15) * 4;
        ushort4v v;
        v[0] = t[d][s4]; v[1] = t[d][s4 + 1]; v[2] = t[d][s4 + 2]; v[3] = t[d][s4 + 3];
        *(ushort4v*)(dst + (size_t)d * S + s4) = v;
    }
}

// ---------------------------------------------------------------------------
// Causal flash attention, LDS-staged with phase-offset single-buffer prefetch.
// grid = (16, B*H). Each block processes TWO complementary q-blocks:
// qi = 31-bx then qi = bx  ->  per-block cost (32-bx)+(bx+1) = 33 tiles for
// every block (perfect static balance; 1024 blocks = 4/CU all co-resident).
// 4 waves x 16 q-rows, KV tiles of 64. K(kb+1) staged after post-QK barrier
// (covered by softmax+PV), V(kb+1) after post-PV barrier (covered by next QK).
// Q pre-scaled by 1/sqrt(D)*log2e -> base-2 softmax. LDS 40KB -> 4 blocks/CU.
// ---------------------------------------------------------------------------
template <bool DIAG>
DEV void flash_core(int kb, int lq, int lm, int qcol,
                    const u16* __restrict__ sKf, const u16* __restrict__ sVf,
                    const short8 qf[4], f32x4 oacc[8],
                    float& mprev, float& lsum, u16* __restrict__ sPw,
                    f32x4 sacc[4])
{
    for (int nt = 0; nt < 4; ++nt) sacc[nt] = (f32x4){0.f, 0.f, 0.f, 0.f};
    for (int nt = 0; nt < 4; ++nt)
        for (int kc = 0; kc < 4; ++kc) {
            short8 kf = *(const short8*)(sKf + (nt * 16 + lm) * 128 +
                                         (((kc * 4 + lq) ^ lm) << 3));
            sacc[nt] = __builtin_amdgcn_mfma_f32_16x16x32_bf16(kf, qf[kc], sacc[nt], 0, 0, 0);
        }
}

DEV void flash_softmax_pv(int lq, int lm,
                          const u16* __restrict__ sVf,
                          f32x4 oacc[8], float& mprev, float& lsum,
                          u16* __restrict__ sPw, f32x4 sacc[4])
{
    float mx = sacc[0][0];
    for (int nt = 0; nt < 4; ++nt)
        for (int i = 0; i < 4; ++i) mx = fmaxf(mx, sacc[nt][i]);
    mx = fmaxf(mx, __shfl_xor(mx, 16));
    mx = fmaxf(mx, __shfl_xor(mx, 32));
    float mnew = fmaxf(mprev, mx);
    float alpha = exp2f(mprev - mnew);
    float rs = 0.0f;
    for (int nt = 0; nt < 4; ++nt)
        for (int i = 0; i < 4; ++i) {
            float pv = exp2f(sacc[nt][i] - mnew);   // scores pre-scaled by log2e
            sacc[nt][i] = pv;
            rs += pv;
        }
    rs += __shfl_xor(rs, 16);
    rs += __shfl_xor(rs, 32);
    lsum = lsum * alpha + rs;
    mprev = mnew;

    // P -> per-wave LDS (truncating v_perm pack; P in [0,1])
    for (int nt = 0; nt < 4; ++nt) {
        uint2 pk;
        pk.x = pk_bf_trunc(sacc[nt][0], sacc[nt][1]);
        pk.y = pk_bf_trunc(sacc[nt][2], sacc[nt][3]);
        *(uint2*)(sPw + lm * 64 +
                  ((((nt << 1) + (lq >> 1)) ^ (lm & 7)) << 3) + ((lq & 1) << 2)) = pk;
    }

    float alphar[4];
    for (int i = 0; i < 4; ++i) alphar[i] = __shfl(alpha, lq * 4 + i, 16);
    for (int f = 0; f < 8; ++f)
        for (int i = 0; i < 4; ++i) oacc[f][i] *= alphar[i];

    short8 pf[2];
    for (int kc = 0; kc < 2; ++kc)
        pf[kc] = *(const short8*)(sPw + lm * 64 + (((kc * 4 + lq) ^ (lm & 7)) << 3));
    for (int f = 0; f < 8; ++f)
        for (int kc = 0; kc < 2; ++kc) {
            short8 vf = *(const short8*)(sVf + (f * 16 + lm) * 64 +
                                         (((kc * 4 + lq) ^ (lm & 7)) << 3));
            oacc[f] = __builtin_amdgcn_mfma_f32_16x16x32_bf16(pf[kc], vf, oacc[f], 0, 0, 0);
        }
}

__global__ __launch_bounds__(256, 4) void k_flash(
    const u16* __restrict__ Qh, const u16* __restrict__ Kh,
    const u16* __restrict__ Vt, u16* __restrict__ ctx, int S)
{
    __shared__ u16 sK[64 * 128];                // 16 KB [kv][d], swizzled
    __shared__ u16 sV[128 * 64];                // 16 KB [d][kv], swizzled
    __shared__ u16 sP[4 * 16 * 64];             //  8 KB per-wave regions
    int bh = blockIdx.y;
    int b = bh >> 4, h = bh & 15;
    int tid = threadIdx.x, lane = tid & 63, w = tid >> 6;
    int lm = lane & 15, lq = lane >> 4;
    const u16* qbase = Qh + (size_t)bh * S * 128;
    u16* sPw = &sP[w * 16 * 64];

    int kck = lm ^ (w * 4 + lq);
    const u16* kg = Kh + (size_t)bh * S * 128 + (size_t)(w * 4 + lq) * 128 + kck * 8;
    int hi3 = lane >> 3, c3 = lane & 7;
    int vck = c3 ^ (hi3 & 7);
    const u16* vg = Vt + (size_t)bh * 128 * S + (size_t)(w * 8 + hi3) * S + vck * 8;

    auto stageK = [&](int kb) {
        const u16* g = kg + (size_t)kb * (64 * 128);
        for (int i = 0; i < 4; ++i)
            gl_lds16(g + i * (16 * 128), sK + (i * 16 + w * 4) * 128);
    };
    auto stageV = [&](int kb) {
        const u16* g = vg + kb * 64;
        for (int i = 0; i < 4; ++i)
            gl_lds16(g + (size_t)(i * 32) * S, sV + (i * 32 + w * 8) * 64);
    };

    for (int half = 0; half < 2; ++half) {
        int qi = half == 0 ? 31 - (int)blockIdx.x : (int)blockIdx.x;

        if (half == 1) __syncthreads();        // all waves done with sK/sV

        int q0 = qi * 64 + w * 16;
        short8 qf[4];
        for (int kc = 0; kc < 4; ++kc)
            qf[kc] = *(const short8*)(qbase + (size_t)(q0 + lm) * 128 + kc * 32 + lq * 8);

        f32x4 oacc[8];
        for (int f = 0; f < 8; ++f) oacc[f] = (f32x4){0.f, 0.f, 0.f, 0.f};
        float mprev = -1e30f, lsum = 0.0f;
        int qcol = q0 + lm;

        stageK(0);
        stageV(0);
        __syncthreads();

        f32x4 sacc[4];
        for (int kb = 0; kb < qi; ++kb) {
            flash_core<false>(kb, lq, lm, qcol, sK, sV, qf, oacc, mprev, lsum, sPw, sacc);
            __syncthreads();                   // A: sK free; drains V(kb) loads
            stageK(kb + 1);                    // covered by softmax+PV
            flash_softmax_pv(lq, lm, sV, oacc, mprev, lsum, sPw, sacc);
            __syncthreads();                   // B: sV free; drains K(kb+1) loads
            stageV(kb + 1);                    // covered by next QK
        }
        // diagonal step (masked); sK/sV valid for kb=qi after last barrier
        flash_core<true>(qi, lq, lm, qcol, sK, sV, qf, oacc, mprev, lsum, sPw, sacc);
        for (int nt = 0; nt < 4; ++nt)
            for (int i = 0; i < 4; ++i) {
                int kv = qi * 64 + nt * 16 + lq * 4 + i;
                if (kv > qcol) sacc[nt][i] = -1e30f;
            }
        __syncthreads();                       // drains V(qi) loads
        flash_softmax_pv(lq, lm, sV, oacc, mprev, lsum, sPw, sacc);

        float linv[4];
        for (int i = 0; i < 4; ++i)
            linv[i] = 1.0f / __shfl(lsum, lq * 4 + i, 16);
        u16* obase = ctx + (size_t)b * S * 2048 + h * 128;
        for (int f = 0; f < 8; ++f) {
            int d = f * 16 + lm;
            for (int i = 0; i < 4; ++i) {
                int s = qi * 64 + w * 16 + lq * 4 + i;
                obase[(size_t)s * 2048 + d] = f2bf(oacc[f][i] * linv[i]);
            }
        }
    }
}

// ---------------------------------------------------------------------------
extern "C" void kernel_launch(void* const* d_in, const int* in_sizes, int n_in,
                              void* d_out, int out_size, void* d_ws, size_t ws_size,
                              hipStream_t stream)
{
    const float* x        = (const float*)d_in[0];
    const float* w_qkv    = (const float*)d_in[1];
    const float* w_proj   = (const float*)d_in[2];
    const float* q_norm_w = (const float*)d_in[3];
    const float* k_norm_w = (const float*)d_in[4];
    float* out = (float*)d_out;

    const int B = 4, S = 2048, E = 2048, H = 16;
    const int M  = B * S;        // 8192
    const int N1 = 3 * E;        // 6144
    const int N2 = E;            // 2048
    // 1/sqrt(128) * log2(e)
    const float QSCALE = 0.12751743f;

    char* ws = (char*)d_ws;
    size_t off = 0;
    auto alloc = [&](size_t bytes) {
        char* p = ws + off;
        off += (bytes + 255) & ~(size_t)255;
        return p;
    };
    u16* Wpt  = (u16*)alloc((size_t)E * E * 2);        // live to end
    char* regR = alloc((size_t)M * N1 * 2);
    u16* Wqt  = (u16*)regR;                            //   dead after GEMM1
    u16* ctxp = (u16*)regR;                            //   written by flash
    u16* Qh = (u16*)alloc((size_t)M * E * 2);
    u16* Kh = (u16*)alloc((size_t)M * E * 2);
    u16* Vh = (u16*)alloc((size_t)M * E * 2);
    char* regV = alloc((size_t)M * E * 2);
    u16* xb = (u16*)regV;                              //   dead after GEMM1
    u16* Vt = (u16*)regV;                              //   written by vtrans

    // 0. x -> bf16
    k_x2bf<<<(M * E) / (256 * 8), 256, 0, stream>>>(x, xb);
    // 1. weight transpose/convert
    k_transpose_bf16<<<dim3(N1 / 64, E / 64), 256, 0, stream>>>(w_qkv, Wqt, E, N1);
    k_transpose_bf16<<<dim3(N2 / 64, E / 64), 256, 0, stream>>>(w_proj, Wpt, E, N2);
    // 2. fused QKV projection, scatter to [B,H,S,D]  (256x256 8-phase)
    k_gemm256<0><<<dim3(N1 / 256, M / 256), 512, 0, stream>>>(
        xb, Wqt, Qh, Kh, Vh, nullptr, M, N1, E);
    // 3. RMSNorm + RoPE (Q additionally pre-scaled for base-2 softmax)
    k_normrope<<<(B * H * S) / 4, 256, 0, stream>>>(Qh, q_norm_w, QSCALE);
    k_normrope<<<(B * H * S) / 4, 256, 0, stream>>>(Kh, k_norm_w, 1.0f);
    // 4. transpose V per head (overwrites xb region — xb dead by now)
    k_vtrans<<<dim3(S / 64, B * H), 256, 0, stream>>>(Vh, Vt, S);
    // 5. causal flash attention -> ctx [B,S,H*D]  (paired q-blocks, balanced)
    k_flash<<<dim3(16, B * H), 256, 0, stream>>>(Qh, Kh, Vt, ctxp, S);
    // 6. output projection -> fp32 out  (256x256 8-phase)
    k_gemm256<1><<<dim3(N2 / 256, M / 256), 512, 0, stream>>>(
        ctxp, Wpt, nullptr, nullptr, nullptr, out, M, N2, E);
}